// Round 4
// baseline (3094.843 us; speedup 1.0000x reference)
//
#include <hip/hip_runtime.h>

// UIR_KG — bucket-sorted COO + LDS-accumulator pull, fused bi-interaction layer.
//
// Round-3 evidence: full row-sort scatter wrote 296MB HBM (64B line per random
// 8B write across 150k slow cursors) -> 395us. Pull only needs block-level
// grouping: sort edges into 64-row BUCKETS (NB=2344). Scatter frontiers are
// 2344 hot lines (L2-resident, adjacent writes) and the pull kernel
// accumulates side[] in LDS via ds_add_f32 (rotation-swizzled banks), then
// runs the dense layer + L2-normalize from LDS.
//
// pairs[e] = { col | (row_local<<18), val } — shared by both layers.
// ws: pairs int2[NE] | bcur int[NB] | x1 float[N*32]  (~57.7 MB)

static __device__ __forceinline__ float leaky(float v) {
    return v > 0.0f ? v : 0.01f * v;
}

// ---------------- out[:,0:64] = E ----------------
__global__ void copy_E_kernel(const float* __restrict__ E, float* __restrict__ out, int N) {
    int tid = blockIdx.x * blockDim.x + threadIdx.x;
    if (tid >= N * 16) return;
    int i = tid >> 4, g = tid & 15;
    float4 v = reinterpret_cast<const float4*>(E)[(size_t)i * 16 + g];
    *reinterpret_cast<float4*>(out + (size_t)i * 112 + g * 4) = v;
}

// ---------------- bucket histogram (LDS-binned) ----------------
__global__ void bucket_hist_kernel(const int* __restrict__ rows, int* __restrict__ bcnt,
                                   int NE, int NB) {
    extern __shared__ int h[];
    for (int i = threadIdx.x; i < NB; i += blockDim.x) h[i] = 0;
    __syncthreads();
    for (int e = blockIdx.x * blockDim.x + threadIdx.x; e < NE; e += gridDim.x * blockDim.x)
        atomicAdd(&h[rows[e] >> 6], 1);
    __syncthreads();
    for (int i = threadIdx.x; i < NB; i += blockDim.x) {
        int c = h[i];
        if (c) atomicAdd(&bcnt[i], c);
    }
}

// ---------------- exclusive scan of NB bucket counts (1 block) ----------------
__global__ void scan_bucket_kernel(int* __restrict__ bcur, int NB) {
    __shared__ int s[1024];
    __shared__ int carry;
    if (threadIdx.x == 0) carry = 0;
    __syncthreads();
    for (int c0 = 0; c0 < NB; c0 += 1024) {
        int i = c0 + threadIdx.x;
        int v = (i < NB) ? bcur[i] : 0;
        s[threadIdx.x] = v;
        __syncthreads();
        for (int off = 1; off < 1024; off <<= 1) {
            int t = (threadIdx.x >= (unsigned)off) ? s[threadIdx.x - off] : 0;
            __syncthreads();
            s[threadIdx.x] += t;
            __syncthreads();
        }
        if (i < NB) bcur[i] = s[threadIdx.x] - v + carry;  // exclusive + carry
        int tot = s[1023];
        __syncthreads();
        if (threadIdx.x == 0) carry += tot;
        __syncthreads();
    }
}

// ---------------- scatter into bucket-grouped pairs ----------------
__global__ void scatter_kernel(const int* __restrict__ rows, const int* __restrict__ cols,
                               const float* __restrict__ ev, int* __restrict__ bcur,
                               int2* __restrict__ pairs, int NE) {
    int e = blockIdx.x * blockDim.x + threadIdx.x;
    if (e >= NE) return;
    int r = rows[e];
    int pos = atomicAdd(&bcur[r >> 6], 1);
    pairs[pos] = make_int2(cols[e] | ((r & 63) << 18), __float_as_int(ev[e]));
}

// ---------------- fused bucket pull + bi-interaction layer ----------------
// Phase B: Q=DIN/4 lanes per edge, G=256/Q concurrent edges; gather x[col]
// (float4/lane, 256B/edge contiguous), ds_add_f32 into acc[rl][d] with a
// (+rl mod DIN) rotation so the wave's 64 atomic lanes spread over all banks.
// Phase C: 4 threads/row, interleaved outputs j=tr+4*jj (keeps W-read banks
// distinct across tr), L2-norm via 2-step shfl_xor in the row quad.
template<int DIN, int DOUT>
__global__ __launch_bounds__(256) void pull_layer_kernel(
    const float* __restrict__ x, const int2* __restrict__ pairs,
    const int* __restrict__ bcur,
    const float* __restrict__ W1, const float* __restrict__ b1,
    const float* __restrict__ W2, const float* __restrict__ b2,
    float* __restrict__ xnext, float* __restrict__ out, int out_col0, int N) {
    constexpr int Q  = DIN / 4;
    constexpr int G  = 256 / Q;
    constexpr int LD = DIN + 4;
    constexpr int JT = DOUT / 4;

    __shared__ float acc[64 * DIN];
    __shared__ float sW1[DOUT * LD];
    __shared__ float sW2[DOUT * LD];

    for (int idx = threadIdx.x; idx < DOUT * DIN; idx += 256) {
        int j = idx / DIN, k = idx % DIN;
        sW1[j * LD + k] = W1[idx];
        sW2[j * LD + k] = W2[idx];
    }
    for (int idx = threadIdx.x; idx < 64 * DIN; idx += 256) acc[idx] = 0.f;
    __syncthreads();

    int b     = blockIdx.x;
    int start = b ? bcur[b - 1] : 0;
    int end   = bcur[b];
    int g     = threadIdx.x / Q;
    int q     = threadIdx.x % Q;
    const float4* xv = reinterpret_cast<const float4*>(x);

    for (int e = start + g; e < end; e += G) {
        int2 p  = pairs[e];
        int col = p.x & 0x3FFFF;
        int rl  = p.x >> 18;
        float v = __int_as_float(p.y);
        float4 gx = xv[(size_t)col * Q + q];
        int base = rl * DIN;
        atomicAdd(&acc[base + ((4 * q + 0 + rl) & (DIN - 1))], v * gx.x);
        atomicAdd(&acc[base + ((4 * q + 1 + rl) & (DIN - 1))], v * gx.y);
        atomicAdd(&acc[base + ((4 * q + 2 + rl) & (DIN - 1))], v * gx.z);
        atomicAdd(&acc[base + ((4 * q + 3 + rl) & (DIN - 1))], v * gx.w);
    }
    __syncthreads();

    int r   = threadIdx.x >> 2;
    int tr  = threadIdx.x & 3;
    int row = b * 64 + r;
    if (row >= N) return;

    float a1[JT], a2[JT];
#pragma unroll
    for (int jj = 0; jj < JT; jj++) {
        a1[jj] = b1[tr + 4 * jj];
        a2[jj] = b2[tr + 4 * jj];
    }
    const float4* xr4 = reinterpret_cast<const float4*>(x + (size_t)row * DIN);
#pragma unroll
    for (int k4 = 0; k4 < DIN / 4; k4++) {
        float4 xr = xr4[k4];
        float s0 = acc[r * DIN + ((4 * k4 + 0 + r) & (DIN - 1))];
        float s1 = acc[r * DIN + ((4 * k4 + 1 + r) & (DIN - 1))];
        float s2 = acc[r * DIN + ((4 * k4 + 2 + r) & (DIN - 1))];
        float s3 = acc[r * DIN + ((4 * k4 + 3 + r) & (DIN - 1))];
        float h1_[4] = {xr.x + s0, xr.y + s1, xr.z + s2, xr.w + s3};
        float h2_[4] = {xr.x * s0, xr.y * s1, xr.z * s2, xr.w * s3};
#pragma unroll
        for (int jj = 0; jj < JT; jj++) {
            int j = tr + 4 * jj;
            const float* w1 = &sW1[j * LD + 4 * k4];
            const float* w2 = &sW2[j * LD + 4 * k4];
            a1[jj] += h1_[0] * w1[0] + h1_[1] * w1[1] + h1_[2] * w1[2] + h1_[3] * w1[3];
            a2[jj] += h2_[0] * w2[0] + h2_[1] * w2[1] + h2_[2] * w2[2] + h2_[3] * w2[3];
        }
    }
    float y[JT], nrm = 0.f;
#pragma unroll
    for (int jj = 0; jj < JT; jj++) {
        float v = leaky(a1[jj]) + leaky(a2[jj]);
        y[jj] = v;
        nrm += v * v;
    }
    nrm += __shfl_xor(nrm, 1, 64);
    nrm += __shfl_xor(nrm, 2, 64);
    float inv = 1.0f / fmaxf(sqrtf(nrm), 1e-12f);
    float* o = out + (size_t)row * 112 + out_col0;
#pragma unroll
    for (int jj = 0; jj < JT; jj++) {
        int j = tr + 4 * jj;
        if (xnext) xnext[(size_t)row * DOUT + j] = y[jj];
        o[j] = y[jj] * inv;
    }
}

extern "C" void kernel_launch(void* const* d_in, const int* in_sizes, int n_in,
                              void* d_out, int out_size, void* d_ws, size_t ws_size,
                              hipStream_t stream) {
    const float* Eemb = (const float*)d_in[0];
    const float* ev   = (const float*)d_in[1];
    const int*   rows = (const int*)d_in[2];
    const int*   cols = (const int*)d_in[3];
    const float* W1_0 = (const float*)d_in[4];
    const float* b1_0 = (const float*)d_in[5];
    const float* W2_0 = (const float*)d_in[6];
    const float* b2_0 = (const float*)d_in[7];
    const float* W1_1 = (const float*)d_in[8];
    const float* b1_1 = (const float*)d_in[9];
    const float* W2_1 = (const float*)d_in[10];
    const float* b2_1 = (const float*)d_in[11];
    float* out = (float*)d_out;

    int N  = in_sizes[0] / 64;
    int NE = in_sizes[1];
    int NB = (N + 63) / 64;

    size_t pairs_b = (size_t)NE * sizeof(int2);
    size_t bcur_b  = ((size_t)NB * sizeof(int) + 255) & ~(size_t)255;

    int2*  pairs = (int2*)d_ws;
    int*   bcur  = (int*)((char*)d_ws + pairs_b);
    float* x1    = (float*)((char*)d_ws + pairs_b + bcur_b);

    hipMemsetAsync(bcur, 0, (size_t)NB * sizeof(int), stream);

    copy_E_kernel<<<(N * 16 + 255) / 256, 256, 0, stream>>>(Eemb, out, N);

    bucket_hist_kernel<<<256, 1024, NB * sizeof(int), stream>>>(rows, bcur, NE, NB);
    scan_bucket_kernel<<<1, 1024, 0, stream>>>(bcur, NB);
    scatter_kernel<<<(NE + 1023) / 1024, 1024, 0, stream>>>(rows, cols, ev, bcur, pairs, NE);

    pull_layer_kernel<64, 32><<<NB, 256, 0, stream>>>(
        Eemb, pairs, bcur, W1_0, b1_0, W2_0, b2_0, x1, out, 64, N);
    pull_layer_kernel<32, 16><<<NB, 256, 0, stream>>>(
        x1, pairs, bcur, W1_1, b1_1, W2_1, b2_1, nullptr, out, 96, N);
}

// Round 5
// 859.805 us; speedup vs baseline: 3.5995x; 3.5995x over previous
//
#include <hip/hip_runtime.h>

// UIR_KG round 5 — bucket-scatter (L2-hot frontiers) + per-bucket counting
// sort to full row order + round-3 register-accumulator pull kernels.
//
// Evidence: r3 full-row scatter = 395us (296MB write-allocate, 150k cold
// frontiers). r4 LDS-atomic pull = 1707us (latency-bound, 16 streams/block).
// Fix: scatter to 2344 64-row buckets (hot frontiers), then per-bucket
// counting sort (reads sequential, writes within 16KB L2-hot window), then
// the proven r3 pull with 4 gathers in flight. tmp pairs live in d_out
// (38.4MB < 67MB, dead until copy_E), ws keeps the proven 58.2MB layout.
//
// ws: pairs int2[NE] | row_end int[N] | bcur int[NB] | x1 float[N*32]

static __device__ __forceinline__ float leaky(float v) {
    return v > 0.0f ? v : 0.01f * v;
}

// ---------------- out[:,0:64] = E ----------------
__global__ void copy_E_kernel(const float* __restrict__ E, float* __restrict__ out, int N) {
    int tid = blockIdx.x * blockDim.x + threadIdx.x;
    if (tid >= N * 16) return;
    int i = tid >> 4, g = tid & 15;
    float4 v = reinterpret_cast<const float4*>(E)[(size_t)i * 16 + g];
    *reinterpret_cast<float4*>(out + (size_t)i * 112 + g * 4) = v;
}

// ---------------- bucket histogram (LDS-binned) ----------------
__global__ void bucket_hist_kernel(const int* __restrict__ rows, int* __restrict__ bcnt,
                                   int NE, int NB) {
    extern __shared__ int h[];
    for (int i = threadIdx.x; i < NB; i += blockDim.x) h[i] = 0;
    __syncthreads();
    for (int e = blockIdx.x * blockDim.x + threadIdx.x; e < NE; e += gridDim.x * blockDim.x)
        atomicAdd(&h[rows[e] >> 6], 1);
    __syncthreads();
    for (int i = threadIdx.x; i < NB; i += blockDim.x) {
        int c = h[i];
        if (c) atomicAdd(&bcnt[i], c);
    }
}

// ---------------- exclusive scan of NB bucket counts (1 block) ----------------
__global__ void scan_bucket_kernel(int* __restrict__ bcur, int NB) {
    __shared__ int s[1024];
    __shared__ int carry;
    if (threadIdx.x == 0) carry = 0;
    __syncthreads();
    for (int c0 = 0; c0 < NB; c0 += 1024) {
        int i = c0 + threadIdx.x;
        int v = (i < NB) ? bcur[i] : 0;
        s[threadIdx.x] = v;
        __syncthreads();
        for (int off = 1; off < 1024; off <<= 1) {
            int t = (threadIdx.x >= (unsigned)off) ? s[threadIdx.x - off] : 0;
            __syncthreads();
            s[threadIdx.x] += t;
            __syncthreads();
        }
        if (i < NB) bcur[i] = s[threadIdx.x] - v + carry;  // exclusive + carry
        int tot = s[1023];
        __syncthreads();
        if (threadIdx.x == 0) carry += tot;
        __syncthreads();
    }
}

// ---------------- scatter into bucket-grouped tmp (in d_out) ----------------
__global__ void bucket_scatter_kernel(const int* __restrict__ rows, const int* __restrict__ cols,
                                      const float* __restrict__ ev, int* __restrict__ bcur,
                                      int2* __restrict__ tmp, int NE) {
    int e = blockIdx.x * blockDim.x + threadIdx.x;
    if (e >= NE) return;
    int r = rows[e];
    int pos = atomicAdd(&bcur[r >> 6], 1);
    tmp[pos] = make_int2(cols[e] | ((r & 63) << 18), __float_as_int(ev[e]));
}

// ---------------- per-bucket counting sort tmp -> pairs, emit row_end ----------------
__global__ __launch_bounds__(256) void bucket_sort_kernel(
    const int2* __restrict__ tmp, int2* __restrict__ pairs,
    const int* __restrict__ bcur, int* __restrict__ row_end, int N) {
    __shared__ int cnt[64];
    __shared__ int cur[64];
    int b     = blockIdx.x;
    int start = b ? bcur[b - 1] : 0;   // post-scatter: bcur[b] == end of bucket b
    int end   = bcur[b];
    if (threadIdx.x < 64) cnt[threadIdx.x] = 0;
    __syncthreads();
    for (int e = start + threadIdx.x; e < end; e += 256)
        atomicAdd(&cnt[tmp[e].x >> 18], 1);
    __syncthreads();
    if (threadIdx.x < 64) {  // wave 0: inclusive shfl scan over 64 counters
        int v = cnt[threadIdx.x];
        int inc = v;
#pragma unroll
        for (int off = 1; off < 64; off <<= 1) {
            int t = __shfl_up(inc, off, 64);
            if (threadIdx.x >= (unsigned)off) inc += t;
        }
        cur[threadIdx.x] = start + inc - v;  // exclusive within bucket + base
        int row = b * 64 + threadIdx.x;
        if (row < N) row_end[row] = start + inc;
    }
    __syncthreads();
    for (int e = start + threadIdx.x; e < end; e += 256) {
        int2 p = tmp[e];
        int pos = atomicAdd(&cur[p.x >> 18], 1);
        pairs[pos] = make_int2(p.x & 0x3FFFF, p.y);
    }
}

// ---------------- fused pull-spmm + bi-interaction layer (r3 + unroll-4) ----------------
template<int DIN, int DOUT>
__global__ __launch_bounds__(256) void pull_layer_kernel(
    const float* __restrict__ x, const int2* __restrict__ pairs,
    const int* __restrict__ row_end,
    const float* __restrict__ W1, const float* __restrict__ b1,
    const float* __restrict__ W2, const float* __restrict__ b2,
    float* __restrict__ xnext,  // unnormalized x' (null on last layer)
    float* __restrict__ out, int out_col0, int N) {
    constexpr int Q   = DIN / 4;
    constexpr int RPB = 256 / Q;
    constexpr int LD  = DIN + 4;
    constexpr int LD4 = LD / 4;
    static_assert(DOUT == 2 * Q, "thread owns exactly 2 output dims");

    __shared__ float sW1[DOUT * LD];
    __shared__ float sW2[DOUT * LD];
    __shared__ float hb[2][RPB][LD];

    for (int idx = threadIdx.x; idx < DOUT * DIN; idx += 256) {
        int j = idx / DIN, k = idx % DIN;
        sW1[j * LD + k] = W1[idx];
        sW2[j * LD + k] = W2[idx];
    }

    int lr  = threadIdx.x / Q;
    int q   = threadIdx.x % Q;
    int row = blockIdx.x * RPB + lr;

    if (row < N) {
        int start = row ? row_end[row - 1] : 0;
        int end   = row_end[row];
        const float4* xv = reinterpret_cast<const float4*>(x);
        float4 acc = make_float4(0.f, 0.f, 0.f, 0.f);
        int e = start;
        for (; e + 3 < end; e += 4) {  // 4 gathers in flight
            int2 p0 = pairs[e];
            int2 p1 = pairs[e + 1];
            int2 p2 = pairs[e + 2];
            int2 p3 = pairs[e + 3];
            float4 g0 = xv[(size_t)p0.x * Q + q];
            float4 g1 = xv[(size_t)p1.x * Q + q];
            float4 g2 = xv[(size_t)p2.x * Q + q];
            float4 g3 = xv[(size_t)p3.x * Q + q];
            float v0 = __int_as_float(p0.y), v1 = __int_as_float(p1.y);
            float v2 = __int_as_float(p2.y), v3 = __int_as_float(p3.y);
            acc.x += v0 * g0.x; acc.y += v0 * g0.y; acc.z += v0 * g0.z; acc.w += v0 * g0.w;
            acc.x += v1 * g1.x; acc.y += v1 * g1.y; acc.z += v1 * g1.z; acc.w += v1 * g1.w;
            acc.x += v2 * g2.x; acc.y += v2 * g2.y; acc.z += v2 * g2.z; acc.w += v2 * g2.w;
            acc.x += v3 * g3.x; acc.y += v3 * g3.y; acc.z += v3 * g3.z; acc.w += v3 * g3.w;
        }
        for (; e < end; e++) {
            int2 p0 = pairs[e];
            float4 g0 = xv[(size_t)p0.x * Q + q];
            float v0 = __int_as_float(p0.y);
            acc.x += v0 * g0.x; acc.y += v0 * g0.y; acc.z += v0 * g0.z; acc.w += v0 * g0.w;
        }
        float4 xr = xv[(size_t)row * Q + q];
        float4 h1 = make_float4(xr.x + acc.x, xr.y + acc.y, xr.z + acc.z, xr.w + acc.w);
        float4 h2 = make_float4(xr.x * acc.x, xr.y * acc.y, xr.z * acc.z, xr.w * acc.w);
        *reinterpret_cast<float4*>(&hb[0][lr][q * 4]) = h1;
        *reinterpret_cast<float4*>(&hb[1][lr][q * 4]) = h2;
    }
    __syncthreads();
    if (row >= N) return;

    float a0 = b1[q], a1 = b1[q + Q], a2 = b2[q], a3 = b2[q + Q];
    const float4* w1v = reinterpret_cast<const float4*>(sW1);
    const float4* w2v = reinterpret_cast<const float4*>(sW2);
    const float4* h1v = reinterpret_cast<const float4*>(&hb[0][lr][0]);
    const float4* h2v = reinterpret_cast<const float4*>(&hb[1][lr][0]);
#pragma unroll
    for (int k4 = 0; k4 < DIN / 4; k4++) {
        float4 h1 = h1v[k4];
        float4 h2 = h2v[k4];
        float4 wa = w1v[q * LD4 + k4];
        float4 wb = w1v[(q + Q) * LD4 + k4];
        float4 wc = w2v[q * LD4 + k4];
        float4 wd = w2v[(q + Q) * LD4 + k4];
        a0 += h1.x * wa.x + h1.y * wa.y + h1.z * wa.z + h1.w * wa.w;
        a1 += h1.x * wb.x + h1.y * wb.y + h1.z * wb.z + h1.w * wb.w;
        a2 += h2.x * wc.x + h2.y * wc.y + h2.z * wc.z + h2.w * wc.w;
        a3 += h2.x * wd.x + h2.y * wd.y + h2.z * wd.z + h2.w * wd.w;
    }
    float y0 = leaky(a0) + leaky(a2);
    float y1 = leaky(a1) + leaky(a3);
    float nrm = y0 * y0 + y1 * y1;
#pragma unroll
    for (int m = 1; m < Q; m <<= 1) nrm += __shfl_xor(nrm, m, 64);
    float inv = 1.0f / fmaxf(sqrtf(nrm), 1e-12f);
    if (xnext) {
        xnext[(size_t)row * DOUT + q]     = y0;
        xnext[(size_t)row * DOUT + q + Q] = y1;
    }
    float* o = out + (size_t)row * 112 + out_col0;
    o[q]     = y0 * inv;
    o[q + Q] = y1 * inv;
}

extern "C" void kernel_launch(void* const* d_in, const int* in_sizes, int n_in,
                              void* d_out, int out_size, void* d_ws, size_t ws_size,
                              hipStream_t stream) {
    const float* Eemb = (const float*)d_in[0];
    const float* ev   = (const float*)d_in[1];
    const int*   rows = (const int*)d_in[2];
    const int*   cols = (const int*)d_in[3];
    const float* W1_0 = (const float*)d_in[4];
    const float* b1_0 = (const float*)d_in[5];
    const float* W2_0 = (const float*)d_in[6];
    const float* b2_0 = (const float*)d_in[7];
    const float* W1_1 = (const float*)d_in[8];
    const float* b1_1 = (const float*)d_in[9];
    const float* W2_1 = (const float*)d_in[10];
    const float* b2_1 = (const float*)d_in[11];
    float* out = (float*)d_out;

    int N  = in_sizes[0] / 64;
    int NE = in_sizes[1];
    int NB = (N + 63) / 64;

    size_t pairs_b  = (size_t)NE * sizeof(int2);
    size_t rowend_b = ((size_t)N * sizeof(int) + 255) & ~(size_t)255;
    size_t bcur_b   = ((size_t)NB * sizeof(int) + 255) & ~(size_t)255;

    int2*  pairs   = (int2*)d_ws;
    int*   row_end = (int*)((char*)d_ws + pairs_b);
    int*   bcur    = (int*)((char*)d_ws + pairs_b + rowend_b);
    float* x1      = (float*)((char*)d_ws + pairs_b + rowend_b + bcur_b);

    int2* tmp = (int2*)d_out;  // 38.4MB scratch, dead before copy_E

    hipMemsetAsync(bcur, 0, (size_t)NB * sizeof(int), stream);
    bucket_hist_kernel<<<256, 1024, NB * sizeof(int), stream>>>(rows, bcur, NE, NB);
    scan_bucket_kernel<<<1, 1024, 0, stream>>>(bcur, NB);
    bucket_scatter_kernel<<<(NE + 1023) / 1024, 1024, 0, stream>>>(rows, cols, ev, bcur, tmp, NE);
    bucket_sort_kernel<<<NB, 256, 0, stream>>>(tmp, pairs, bcur, row_end, N);

    copy_E_kernel<<<(N * 16 + 255) / 256, 256, 0, stream>>>(Eemb, out, N);

    pull_layer_kernel<64, 32><<<(N + 15) / 16, 256, 0, stream>>>(
        Eemb, pairs, row_end, W1_0, b1_0, W2_0, b2_0, x1, out, 64, N);
    pull_layer_kernel<32, 16><<<(N + 31) / 32, 256, 0, stream>>>(
        x1, pairs, row_end, W1_1, b1_1, W2_1, b2_1, nullptr, out, 96, N);
}

// Round 6
// 404.649 us; speedup vs baseline: 7.6482x; 2.1248x over previous
//
#include <hip/hip_runtime.h>

// UIR_KG round 6 — LDS-staged group-and-flush CSR build + r5 pull kernels.
//
// Evidence r3/r5: random per-lane 8B scatter writes cost a full 64B HBM line
// each regardless of logical bucket locality (per-XCD L2 write-allocate +
// stream eviction): 296MB/395us (r3), 260MB/518us (r5). Only WAVE-contiguous
// writes fix it. Here each block groups 4096 edges in LDS by 1024-row
// partition (147 of them), reserves space with ONE atomic per (block,
// partition), and flushes ~28-edge (224B) contiguous runs. Then one block per
// partition row-sorts its ~32.7K edges (random 8B writes confined to a 256KB
// single-block L2 window — the pattern r5's bucket_sort proved cheap), also
// emitting row_end[] CSR. Pull kernels unchanged from r5.
//
// ws: pairs int2[NE] | row_end int[N] | pcnt/pbase/gcur int[256] | x1 f[N*32]
// tmp (partition-grouped pairs) lives in d_out: dead until copy_E.

constexpr int PSHIFT = 10;            // 1024 rows per partition
constexpr int PROWS  = 1 << PSHIFT;
constexpr int GF_T   = 1024;          // group_flush threads
constexpr int GF_E   = 4096;          // edges per group_flush block
constexpr int GF_K   = GF_E / GF_T;   // 4 edges per thread

static __device__ __forceinline__ float leaky(float v) {
    return v > 0.0f ? v : 0.01f * v;
}

// ---------------- out[:,0:64] = E ----------------
__global__ void copy_E_kernel(const float* __restrict__ E, float* __restrict__ out, int N) {
    int tid = blockIdx.x * blockDim.x + threadIdx.x;
    if (tid >= N * 16) return;
    int i = tid >> 4, g = tid & 15;
    float4 v = reinterpret_cast<const float4*>(E)[(size_t)i * 16 + g];
    *reinterpret_cast<float4*>(out + (size_t)i * 112 + g * 4) = v;
}

// ---------------- global partition histogram (LDS-binned) ----------------
__global__ void part_hist_kernel(const int* __restrict__ rows, int* __restrict__ pcnt,
                                 int NE, int P) {
    extern __shared__ int h[];
    for (int i = threadIdx.x; i < P; i += blockDim.x) h[i] = 0;
    __syncthreads();
    for (int e = blockIdx.x * blockDim.x + threadIdx.x; e < NE; e += gridDim.x * blockDim.x)
        atomicAdd(&h[rows[e] >> PSHIFT], 1);
    __syncthreads();
    for (int i = threadIdx.x; i < P; i += blockDim.x) {
        int c = h[i];
        if (c) atomicAdd(&pcnt[i], c);
    }
}

// ---------------- scan partition counts -> pbase[P+1], gcur ----------------
__global__ void part_scan_kernel(const int* __restrict__ pcnt, int* __restrict__ pbase,
                                 int* __restrict__ gcur, int P, int NE) {
    __shared__ int s[256];
    int v = (threadIdx.x < (unsigned)P) ? pcnt[threadIdx.x] : 0;
    s[threadIdx.x] = v;
    __syncthreads();
    for (int off = 1; off < 256; off <<= 1) {
        int t = (threadIdx.x >= (unsigned)off) ? s[threadIdx.x - off] : 0;
        __syncthreads();
        s[threadIdx.x] += t;
        __syncthreads();
    }
    if (threadIdx.x < (unsigned)P) {
        int ex = s[threadIdx.x] - v;
        pbase[threadIdx.x] = ex;
        gcur[threadIdx.x]  = ex;
    }
    if (threadIdx.x == 0) pbase[P] = NE;
}

// ---------------- LDS group + contiguous flush ----------------
__global__ __launch_bounds__(GF_T) void group_flush_kernel(
    const int* __restrict__ rows, const int* __restrict__ cols,
    const float* __restrict__ ev, int* __restrict__ gcur,
    int2* __restrict__ tmp, int NE, int P) {
    __shared__ int2 staged[GF_E];            // 32KB
    __shared__ unsigned short sp[GF_E];      // 8KB: partition of each slot
    __shared__ int hist[256], runstart[256], hcur[256], gbase[256], scanb[256];

    int e0  = blockIdx.x * GF_E;
    int cnt = min(GF_E, NE - e0);

    if (threadIdx.x < 256) hist[threadIdx.x] = 0;
    __syncthreads();

    int pk[GF_K], ck[GF_K], rk[GF_K];
    float vk[GF_K];
#pragma unroll
    for (int k = 0; k < GF_K; k++) {
        int idx = threadIdx.x + k * GF_T;
        if (idx < cnt) {
            int r = rows[e0 + idx];
            pk[k] = r >> PSHIFT;
            rk[k] = r & (PROWS - 1);
            ck[k] = cols[e0 + idx];
            vk[k] = ev[e0 + idx];
            atomicAdd(&hist[pk[k]], 1);
        } else pk[k] = -1;
    }
    __syncthreads();
    if (threadIdx.x < 256) scanb[threadIdx.x] = hist[threadIdx.x];
    __syncthreads();
    for (int off = 1; off < 256; off <<= 1) {
        int t = 0;
        if (threadIdx.x < 256 && threadIdx.x >= (unsigned)off) t = scanb[threadIdx.x - off];
        __syncthreads();
        if (threadIdx.x < 256) scanb[threadIdx.x] += t;
        __syncthreads();
    }
    if (threadIdx.x < 256) {
        int ex = scanb[threadIdx.x] - hist[threadIdx.x];
        runstart[threadIdx.x] = ex;
        hcur[threadIdx.x]     = ex;
    }
    __syncthreads();
#pragma unroll
    for (int k = 0; k < GF_K; k++) {
        if (pk[k] >= 0) {
            int slot = atomicAdd(&hcur[pk[k]], 1);
            staged[slot] = make_int2(ck[k] | (rk[k] << 18), __float_as_int(vk[k]));
            sp[slot] = (unsigned short)pk[k];
        }
    }
    __syncthreads();
    if (threadIdx.x < (unsigned)P) {
        int h = hist[threadIdx.x];
        if (h > 0) gbase[threadIdx.x] = atomicAdd(&gcur[threadIdx.x], h);
    }
    __syncthreads();
#pragma unroll
    for (int k = 0; k < GF_K; k++) {
        int i = threadIdx.x + k * GF_T;
        if (i < cnt) {
            int p = sp[i];
            tmp[gbase[p] + (i - runstart[p])] = staged[i];  // ~224B contiguous runs
        }
    }
}

// ---------------- per-partition row sort, emits row_end ----------------
__global__ __launch_bounds__(1024) void row_sort_kernel(
    const int2* __restrict__ tmp, int2* __restrict__ pairs,
    const int* __restrict__ pbase, int* __restrict__ row_end, int N) {
    __shared__ int hist[PROWS], cur[PROWS], scanb[PROWS];
    int p     = blockIdx.x;
    int start = pbase[p];
    int end   = pbase[p + 1];
    hist[threadIdx.x] = 0;   // blockDim == PROWS == 1024
    __syncthreads();
    for (int e = start + threadIdx.x; e < end; e += 1024)
        atomicAdd(&hist[tmp[e].x >> 18], 1);
    __syncthreads();
    scanb[threadIdx.x] = hist[threadIdx.x];
    __syncthreads();
    for (int off = 1; off < 1024; off <<= 1) {
        int t = (threadIdx.x >= (unsigned)off) ? scanb[threadIdx.x - off] : 0;
        __syncthreads();
        scanb[threadIdx.x] += t;
        __syncthreads();
    }
    int inc = scanb[threadIdx.x];
    cur[threadIdx.x] = start + inc - hist[threadIdx.x];
    int row = (p << PSHIFT) + threadIdx.x;
    if (row < N) row_end[row] = start + inc;
    __syncthreads();
    for (int e = start + threadIdx.x; e < end; e += 1024) {
        int2 t = tmp[e];
        int pos = atomicAdd(&cur[t.x >> 18], 1);
        pairs[pos] = make_int2(t.x & 0x3FFFF, t.y);  // within 256KB L2-hot window
    }
}

// ---------------- fused pull-spmm + bi-interaction layer (r5) ----------------
template<int DIN, int DOUT>
__global__ __launch_bounds__(256) void pull_layer_kernel(
    const float* __restrict__ x, const int2* __restrict__ pairs,
    const int* __restrict__ row_end,
    const float* __restrict__ W1, const float* __restrict__ b1,
    const float* __restrict__ W2, const float* __restrict__ b2,
    float* __restrict__ xnext, float* __restrict__ out, int out_col0, int N) {
    constexpr int Q   = DIN / 4;
    constexpr int RPB = 256 / Q;
    constexpr int LD  = DIN + 4;
    constexpr int LD4 = LD / 4;
    static_assert(DOUT == 2 * Q, "thread owns exactly 2 output dims");

    __shared__ float sW1[DOUT * LD];
    __shared__ float sW2[DOUT * LD];
    __shared__ float hb[2][RPB][LD];

    for (int idx = threadIdx.x; idx < DOUT * DIN; idx += 256) {
        int j = idx / DIN, k = idx % DIN;
        sW1[j * LD + k] = W1[idx];
        sW2[j * LD + k] = W2[idx];
    }

    int lr  = threadIdx.x / Q;
    int q   = threadIdx.x % Q;
    int row = blockIdx.x * RPB + lr;

    if (row < N) {
        int start = row ? row_end[row - 1] : 0;
        int end   = row_end[row];
        const float4* xv = reinterpret_cast<const float4*>(x);
        float4 acc = make_float4(0.f, 0.f, 0.f, 0.f);
        int e = start;
        for (; e + 3 < end; e += 4) {  // 4 gathers in flight
            int2 p0 = pairs[e];
            int2 p1 = pairs[e + 1];
            int2 p2 = pairs[e + 2];
            int2 p3 = pairs[e + 3];
            float4 g0 = xv[(size_t)p0.x * Q + q];
            float4 g1 = xv[(size_t)p1.x * Q + q];
            float4 g2 = xv[(size_t)p2.x * Q + q];
            float4 g3 = xv[(size_t)p3.x * Q + q];
            float v0 = __int_as_float(p0.y), v1 = __int_as_float(p1.y);
            float v2 = __int_as_float(p2.y), v3 = __int_as_float(p3.y);
            acc.x += v0 * g0.x; acc.y += v0 * g0.y; acc.z += v0 * g0.z; acc.w += v0 * g0.w;
            acc.x += v1 * g1.x; acc.y += v1 * g1.y; acc.z += v1 * g1.z; acc.w += v1 * g1.w;
            acc.x += v2 * g2.x; acc.y += v2 * g2.y; acc.z += v2 * g2.z; acc.w += v2 * g2.w;
            acc.x += v3 * g3.x; acc.y += v3 * g3.y; acc.z += v3 * g3.z; acc.w += v3 * g3.w;
        }
        for (; e < end; e++) {
            int2 p0 = pairs[e];
            float4 g0 = xv[(size_t)p0.x * Q + q];
            float v0 = __int_as_float(p0.y);
            acc.x += v0 * g0.x; acc.y += v0 * g0.y; acc.z += v0 * g0.z; acc.w += v0 * g0.w;
        }
        float4 xr = xv[(size_t)row * Q + q];
        float4 h1 = make_float4(xr.x + acc.x, xr.y + acc.y, xr.z + acc.z, xr.w + acc.w);
        float4 h2 = make_float4(xr.x * acc.x, xr.y * acc.y, xr.z * acc.z, xr.w * acc.w);
        *reinterpret_cast<float4*>(&hb[0][lr][q * 4]) = h1;
        *reinterpret_cast<float4*>(&hb[1][lr][q * 4]) = h2;
    }
    __syncthreads();
    if (row >= N) return;

    float a0 = b1[q], a1 = b1[q + Q], a2 = b2[q], a3 = b2[q + Q];
    const float4* w1v = reinterpret_cast<const float4*>(sW1);
    const float4* w2v = reinterpret_cast<const float4*>(sW2);
    const float4* h1v = reinterpret_cast<const float4*>(&hb[0][lr][0]);
    const float4* h2v = reinterpret_cast<const float4*>(&hb[1][lr][0]);
#pragma unroll
    for (int k4 = 0; k4 < DIN / 4; k4++) {
        float4 h1 = h1v[k4];
        float4 h2 = h2v[k4];
        float4 wa = w1v[q * LD4 + k4];
        float4 wb = w1v[(q + Q) * LD4 + k4];
        float4 wc = w2v[q * LD4 + k4];
        float4 wd = w2v[(q + Q) * LD4 + k4];
        a0 += h1.x * wa.x + h1.y * wa.y + h1.z * wa.z + h1.w * wa.w;
        a1 += h1.x * wb.x + h1.y * wb.y + h1.z * wb.z + h1.w * wb.w;
        a2 += h2.x * wc.x + h2.y * wc.y + h2.z * wc.z + h2.w * wc.w;
        a3 += h2.x * wd.x + h2.y * wd.y + h2.z * wd.z + h2.w * wd.w;
    }
    float y0 = leaky(a0) + leaky(a2);
    float y1 = leaky(a1) + leaky(a3);
    float nrm = y0 * y0 + y1 * y1;
#pragma unroll
    for (int m = 1; m < Q; m <<= 1) nrm += __shfl_xor(nrm, m, 64);
    float inv = 1.0f / fmaxf(sqrtf(nrm), 1e-12f);
    if (xnext) {
        xnext[(size_t)row * DOUT + q]     = y0;
        xnext[(size_t)row * DOUT + q + Q] = y1;
    }
    float* o = out + (size_t)row * 112 + out_col0;
    o[q]     = y0 * inv;
    o[q + Q] = y1 * inv;
}

extern "C" void kernel_launch(void* const* d_in, const int* in_sizes, int n_in,
                              void* d_out, int out_size, void* d_ws, size_t ws_size,
                              hipStream_t stream) {
    const float* Eemb = (const float*)d_in[0];
    const float* ev   = (const float*)d_in[1];
    const int*   rows = (const int*)d_in[2];
    const int*   cols = (const int*)d_in[3];
    const float* W1_0 = (const float*)d_in[4];
    const float* b1_0 = (const float*)d_in[5];
    const float* W2_0 = (const float*)d_in[6];
    const float* b2_0 = (const float*)d_in[7];
    const float* W1_1 = (const float*)d_in[8];
    const float* b1_1 = (const float*)d_in[9];
    const float* W2_1 = (const float*)d_in[10];
    const float* b2_1 = (const float*)d_in[11];
    float* out = (float*)d_out;

    int N  = in_sizes[0] / 64;
    int NE = in_sizes[1];
    int P  = (N + PROWS - 1) >> PSHIFT;   // 147

    size_t pairs_b  = (size_t)NE * sizeof(int2);
    size_t rowend_b = ((size_t)N * sizeof(int) + 255) & ~(size_t)255;
    size_t small_b  = 3 * 256 * sizeof(int);

    int2*  pairs   = (int2*)d_ws;
    int*   row_end = (int*)((char*)d_ws + pairs_b);
    int*   pcnt    = (int*)((char*)d_ws + pairs_b + rowend_b);
    int*   pbase   = pcnt + 256;
    int*   gcur    = pcnt + 512;
    float* x1      = (float*)((char*)d_ws + pairs_b + rowend_b + small_b);

    int2* tmp = (int2*)d_out;  // 38.4MB scratch, dead until copy_E

    hipMemsetAsync(pcnt, 0, 256 * sizeof(int), stream);
    part_hist_kernel<<<256, 1024, P * sizeof(int), stream>>>(rows, pcnt, NE, P);
    part_scan_kernel<<<1, 256, 0, stream>>>(pcnt, pbase, gcur, P, NE);
    group_flush_kernel<<<(NE + GF_E - 1) / GF_E, GF_T, 0, stream>>>(
        rows, cols, ev, gcur, tmp, NE, P);
    row_sort_kernel<<<P, 1024, 0, stream>>>(tmp, pairs, pbase, row_end, N);

    copy_E_kernel<<<(N * 16 + 255) / 256, 256, 0, stream>>>(Eemb, out, N);

    pull_layer_kernel<64, 32><<<(N + 15) / 16, 256, 0, stream>>>(
        Eemb, pairs, row_end, W1_0, b1_0, W2_0, b2_0, x1, out, 64, N);
    pull_layer_kernel<32, 16><<<(N + 31) / 32, 256, 0, stream>>>(
        x1, pairs, row_end, W1_1, b1_1, W2_1, b2_1, nullptr, out, 96, N);
}

// Round 7
// 339.458 us; speedup vs baseline: 9.1170x; 1.1920x over previous
//
#include <hip/hip_runtime.h>

// UIR_KG round 7 — r6 pipeline + bf16 gather mirror for layer-0 pull.
//
// r6 evidence: pull0 = 193us, FETCH 590MB (gather 1.23GB logical, ~half
// past L2) — gather-byte-bound. Fix: gather from a bf16 copy of E (128B/edge
// instead of 256B); own-row x term stays f32 so only the side-sum sees bf16
// noise (~1e-3 at output vs 1.97e-2 threshold). Layer 1 stays f32 this round
// to measure precision headroom before converting it too.
//
// ws: pairs int2[NE] | row_end int[N] | pcnt/pbase/gcur int[256] | x1 f[N*32]
//     | Ebf ushort[N*64]   (fallback: skip Ebf, use f32 pull0)
// tmp (partition-grouped pairs) lives in d_out: dead until copy_E.

constexpr int PSHIFT = 10;            // 1024 rows per partition
constexpr int PROWS  = 1 << PSHIFT;
constexpr int GF_T   = 1024;          // group_flush threads
constexpr int GF_E   = 4096;          // edges per group_flush block
constexpr int GF_K   = GF_E / GF_T;   // 4 edges per thread

static __device__ __forceinline__ float leaky(float v) {
    return v > 0.0f ? v : 0.01f * v;
}

static __device__ __forceinline__ unsigned short f2bf_rne(float f) {
    unsigned u = __float_as_uint(f);
    return (unsigned short)((u + 0x7FFF + ((u >> 16) & 1)) >> 16);
}

static __device__ __forceinline__ float bf2f(unsigned short s) {
    return __uint_as_float(((unsigned)s) << 16);
}

// ---------------- out[:,0:64] = E, and Ebf = bf16(E) ----------------
__global__ void copy_E_kernel(const float* __restrict__ E, float* __restrict__ out,
                              unsigned short* __restrict__ Ebf, int N) {
    int tid = blockIdx.x * blockDim.x + threadIdx.x;
    if (tid >= N * 16) return;
    int i = tid >> 4, g = tid & 15;
    float4 v = reinterpret_cast<const float4*>(E)[(size_t)i * 16 + g];
    *reinterpret_cast<float4*>(out + (size_t)i * 112 + g * 4) = v;
    if (Ebf) {
        ushort4 b;
        b.x = f2bf_rne(v.x); b.y = f2bf_rne(v.y);
        b.z = f2bf_rne(v.z); b.w = f2bf_rne(v.w);
        *reinterpret_cast<ushort4*>(Ebf + (size_t)i * 64 + g * 4) = b;
    }
}

// ---------------- global partition histogram (LDS-binned) ----------------
__global__ void part_hist_kernel(const int* __restrict__ rows, int* __restrict__ pcnt,
                                 int NE, int P) {
    extern __shared__ int h[];
    for (int i = threadIdx.x; i < P; i += blockDim.x) h[i] = 0;
    __syncthreads();
    for (int e = blockIdx.x * blockDim.x + threadIdx.x; e < NE; e += gridDim.x * blockDim.x)
        atomicAdd(&h[rows[e] >> PSHIFT], 1);
    __syncthreads();
    for (int i = threadIdx.x; i < P; i += blockDim.x) {
        int c = h[i];
        if (c) atomicAdd(&pcnt[i], c);
    }
}

// ---------------- scan partition counts -> pbase[P+1], gcur ----------------
__global__ void part_scan_kernel(const int* __restrict__ pcnt, int* __restrict__ pbase,
                                 int* __restrict__ gcur, int P, int NE) {
    __shared__ int s[256];
    int v = (threadIdx.x < (unsigned)P) ? pcnt[threadIdx.x] : 0;
    s[threadIdx.x] = v;
    __syncthreads();
    for (int off = 1; off < 256; off <<= 1) {
        int t = (threadIdx.x >= (unsigned)off) ? s[threadIdx.x - off] : 0;
        __syncthreads();
        s[threadIdx.x] += t;
        __syncthreads();
    }
    if (threadIdx.x < (unsigned)P) {
        int ex = s[threadIdx.x] - v;
        pbase[threadIdx.x] = ex;
        gcur[threadIdx.x]  = ex;
    }
    if (threadIdx.x == 0) pbase[P] = NE;
}

// ---------------- LDS group + contiguous flush ----------------
__global__ __launch_bounds__(GF_T) void group_flush_kernel(
    const int* __restrict__ rows, const int* __restrict__ cols,
    const float* __restrict__ ev, int* __restrict__ gcur,
    int2* __restrict__ tmp, int NE, int P) {
    __shared__ int2 staged[GF_E];            // 32KB
    __shared__ unsigned short sp[GF_E];      // 8KB
    __shared__ int hist[256], runstart[256], hcur[256], gbase[256], scanb[256];

    int e0  = blockIdx.x * GF_E;
    int cnt = min(GF_E, NE - e0);

    if (threadIdx.x < 256) hist[threadIdx.x] = 0;
    __syncthreads();

    int pk[GF_K], ck[GF_K], rk[GF_K];
    float vk[GF_K];
#pragma unroll
    for (int k = 0; k < GF_K; k++) {
        int idx = threadIdx.x + k * GF_T;
        if (idx < cnt) {
            int r = rows[e0 + idx];
            pk[k] = r >> PSHIFT;
            rk[k] = r & (PROWS - 1);
            ck[k] = cols[e0 + idx];
            vk[k] = ev[e0 + idx];
            atomicAdd(&hist[pk[k]], 1);
        } else pk[k] = -1;
    }
    __syncthreads();
    if (threadIdx.x < 256) scanb[threadIdx.x] = hist[threadIdx.x];
    __syncthreads();
    for (int off = 1; off < 256; off <<= 1) {
        int t = 0;
        if (threadIdx.x < 256 && threadIdx.x >= (unsigned)off) t = scanb[threadIdx.x - off];
        __syncthreads();
        if (threadIdx.x < 256) scanb[threadIdx.x] += t;
        __syncthreads();
    }
    if (threadIdx.x < 256) {
        int ex = scanb[threadIdx.x] - hist[threadIdx.x];
        runstart[threadIdx.x] = ex;
        hcur[threadIdx.x]     = ex;
    }
    __syncthreads();
#pragma unroll
    for (int k = 0; k < GF_K; k++) {
        if (pk[k] >= 0) {
            int slot = atomicAdd(&hcur[pk[k]], 1);
            staged[slot] = make_int2(ck[k] | (rk[k] << 18), __float_as_int(vk[k]));
            sp[slot] = (unsigned short)pk[k];
        }
    }
    __syncthreads();
    if (threadIdx.x < (unsigned)P) {
        int h = hist[threadIdx.x];
        if (h > 0) gbase[threadIdx.x] = atomicAdd(&gcur[threadIdx.x], h);
    }
    __syncthreads();
#pragma unroll
    for (int k = 0; k < GF_K; k++) {
        int i = threadIdx.x + k * GF_T;
        if (i < cnt) {
            int p = sp[i];
            tmp[gbase[p] + (i - runstart[p])] = staged[i];  // contiguous runs
        }
    }
}

// ---------------- per-partition row sort, emits row_end ----------------
__global__ __launch_bounds__(1024) void row_sort_kernel(
    const int2* __restrict__ tmp, int2* __restrict__ pairs,
    const int* __restrict__ pbase, int* __restrict__ row_end, int N) {
    __shared__ int hist[PROWS], cur[PROWS], scanb[PROWS];
    int p     = blockIdx.x;
    int start = pbase[p];
    int end   = pbase[p + 1];
    hist[threadIdx.x] = 0;
    __syncthreads();
    for (int e = start + threadIdx.x; e < end; e += 1024)
        atomicAdd(&hist[tmp[e].x >> 18], 1);
    __syncthreads();
    scanb[threadIdx.x] = hist[threadIdx.x];
    __syncthreads();
    for (int off = 1; off < 1024; off <<= 1) {
        int t = (threadIdx.x >= (unsigned)off) ? scanb[threadIdx.x - off] : 0;
        __syncthreads();
        scanb[threadIdx.x] += t;
        __syncthreads();
    }
    int inc = scanb[threadIdx.x];
    cur[threadIdx.x] = start + inc - hist[threadIdx.x];
    int row = (p << PSHIFT) + threadIdx.x;
    if (row < N) row_end[row] = start + inc;
    __syncthreads();
    for (int e = start + threadIdx.x; e < end; e += 1024) {
        int2 t = tmp[e];
        int pos = atomicAdd(&cur[t.x >> 18], 1);
        pairs[pos] = make_int2(t.x & 0x3FFFF, t.y);
    }
}

// ---------------- bf16-gather pull + layer (layer 0) ----------------
template<int DIN, int DOUT>
__global__ __launch_bounds__(256) void pull_layer_bf16_kernel(
    const float* __restrict__ x,                 // f32 own-row source
    const unsigned short* __restrict__ xb,       // bf16 gather source [N][DIN]
    const int2* __restrict__ pairs, const int* __restrict__ row_end,
    const float* __restrict__ W1, const float* __restrict__ b1,
    const float* __restrict__ W2, const float* __restrict__ b2,
    float* __restrict__ xnext, float* __restrict__ out, int out_col0, int N) {
    constexpr int Q   = DIN / 4;
    constexpr int RPB = 256 / Q;
    constexpr int LD  = DIN + 4;
    constexpr int LD4 = LD / 4;
    static_assert(DOUT == 2 * Q, "thread owns exactly 2 output dims");

    __shared__ float sW1[DOUT * LD];
    __shared__ float sW2[DOUT * LD];
    __shared__ float hb[2][RPB][LD];

    for (int idx = threadIdx.x; idx < DOUT * DIN; idx += 256) {
        int j = idx / DIN, k = idx % DIN;
        sW1[j * LD + k] = W1[idx];
        sW2[j * LD + k] = W2[idx];
    }

    int lr  = threadIdx.x / Q;
    int q   = threadIdx.x % Q;
    int row = blockIdx.x * RPB + lr;

    if (row < N) {
        int start = row ? row_end[row - 1] : 0;
        int end   = row_end[row];
        const ushort4* xbv = reinterpret_cast<const ushort4*>(xb);
        float4 acc = make_float4(0.f, 0.f, 0.f, 0.f);
        int e = start;
        for (; e + 7 < end; e += 8) {  // 8 gathers in flight (8B/lane)
            int2 p[8]; ushort4 g[8];
#pragma unroll
            for (int k = 0; k < 8; k++) p[k] = pairs[e + k];
#pragma unroll
            for (int k = 0; k < 8; k++) g[k] = xbv[(size_t)p[k].x * Q + q];
#pragma unroll
            for (int k = 0; k < 8; k++) {
                float v = __int_as_float(p[k].y);
                acc.x += v * bf2f(g[k].x); acc.y += v * bf2f(g[k].y);
                acc.z += v * bf2f(g[k].z); acc.w += v * bf2f(g[k].w);
            }
        }
        for (; e + 1 < end; e += 2) {
            int2 p0 = pairs[e], p1 = pairs[e + 1];
            ushort4 g0 = xbv[(size_t)p0.x * Q + q];
            ushort4 g1 = xbv[(size_t)p1.x * Q + q];
            float v0 = __int_as_float(p0.y), v1 = __int_as_float(p1.y);
            acc.x += v0 * bf2f(g0.x); acc.y += v0 * bf2f(g0.y);
            acc.z += v0 * bf2f(g0.z); acc.w += v0 * bf2f(g0.w);
            acc.x += v1 * bf2f(g1.x); acc.y += v1 * bf2f(g1.y);
            acc.z += v1 * bf2f(g1.z); acc.w += v1 * bf2f(g1.w);
        }
        if (e < end) {
            int2 p0 = pairs[e];
            ushort4 g0 = xbv[(size_t)p0.x * Q + q];
            float v0 = __int_as_float(p0.y);
            acc.x += v0 * bf2f(g0.x); acc.y += v0 * bf2f(g0.y);
            acc.z += v0 * bf2f(g0.z); acc.w += v0 * bf2f(g0.w);
        }
        const float4* xv = reinterpret_cast<const float4*>(x);
        float4 xr = xv[(size_t)row * Q + q];
        float4 h1 = make_float4(xr.x + acc.x, xr.y + acc.y, xr.z + acc.z, xr.w + acc.w);
        float4 h2 = make_float4(xr.x * acc.x, xr.y * acc.y, xr.z * acc.z, xr.w * acc.w);
        *reinterpret_cast<float4*>(&hb[0][lr][q * 4]) = h1;
        *reinterpret_cast<float4*>(&hb[1][lr][q * 4]) = h2;
    }
    __syncthreads();
    if (row >= N) return;

    float a0 = b1[q], a1 = b1[q + Q], a2 = b2[q], a3 = b2[q + Q];
    const float4* w1v = reinterpret_cast<const float4*>(sW1);
    const float4* w2v = reinterpret_cast<const float4*>(sW2);
    const float4* h1v = reinterpret_cast<const float4*>(&hb[0][lr][0]);
    const float4* h2v = reinterpret_cast<const float4*>(&hb[1][lr][0]);
#pragma unroll
    for (int k4 = 0; k4 < DIN / 4; k4++) {
        float4 h1 = h1v[k4];
        float4 h2 = h2v[k4];
        float4 wa = w1v[q * LD4 + k4];
        float4 wb = w1v[(q + Q) * LD4 + k4];
        float4 wc = w2v[q * LD4 + k4];
        float4 wd = w2v[(q + Q) * LD4 + k4];
        a0 += h1.x * wa.x + h1.y * wa.y + h1.z * wa.z + h1.w * wa.w;
        a1 += h1.x * wb.x + h1.y * wb.y + h1.z * wb.z + h1.w * wb.w;
        a2 += h2.x * wc.x + h2.y * wc.y + h2.z * wc.z + h2.w * wc.w;
        a3 += h2.x * wd.x + h2.y * wd.y + h2.z * wd.z + h2.w * wd.w;
    }
    float y0 = leaky(a0) + leaky(a2);
    float y1 = leaky(a1) + leaky(a3);
    float nrm = y0 * y0 + y1 * y1;
#pragma unroll
    for (int m = 1; m < Q; m <<= 1) nrm += __shfl_xor(nrm, m, 64);
    float inv = 1.0f / fmaxf(sqrtf(nrm), 1e-12f);
    if (xnext) {
        xnext[(size_t)row * DOUT + q]     = y0;
        xnext[(size_t)row * DOUT + q + Q] = y1;
    }
    float* o = out + (size_t)row * 112 + out_col0;
    o[q]     = y0 * inv;
    o[q + Q] = y1 * inv;
}

// ---------------- f32 pull + layer (layer 1, and layer-0 fallback) ----------------
template<int DIN, int DOUT>
__global__ __launch_bounds__(256) void pull_layer_kernel(
    const float* __restrict__ x, const int2* __restrict__ pairs,
    const int* __restrict__ row_end,
    const float* __restrict__ W1, const float* __restrict__ b1,
    const float* __restrict__ W2, const float* __restrict__ b2,
    float* __restrict__ xnext, float* __restrict__ out, int out_col0, int N) {
    constexpr int Q   = DIN / 4;
    constexpr int RPB = 256 / Q;
    constexpr int LD  = DIN + 4;
    constexpr int LD4 = LD / 4;
    static_assert(DOUT == 2 * Q, "thread owns exactly 2 output dims");

    __shared__ float sW1[DOUT * LD];
    __shared__ float sW2[DOUT * LD];
    __shared__ float hb[2][RPB][LD];

    for (int idx = threadIdx.x; idx < DOUT * DIN; idx += 256) {
        int j = idx / DIN, k = idx % DIN;
        sW1[j * LD + k] = W1[idx];
        sW2[j * LD + k] = W2[idx];
    }

    int lr  = threadIdx.x / Q;
    int q   = threadIdx.x % Q;
    int row = blockIdx.x * RPB + lr;

    if (row < N) {
        int start = row ? row_end[row - 1] : 0;
        int end   = row_end[row];
        const float4* xv = reinterpret_cast<const float4*>(x);
        float4 acc = make_float4(0.f, 0.f, 0.f, 0.f);
        int e = start;
        for (; e + 3 < end; e += 4) {
            int2 p0 = pairs[e];
            int2 p1 = pairs[e + 1];
            int2 p2 = pairs[e + 2];
            int2 p3 = pairs[e + 3];
            float4 g0 = xv[(size_t)p0.x * Q + q];
            float4 g1 = xv[(size_t)p1.x * Q + q];
            float4 g2 = xv[(size_t)p2.x * Q + q];
            float4 g3 = xv[(size_t)p3.x * Q + q];
            float v0 = __int_as_float(p0.y), v1 = __int_as_float(p1.y);
            float v2 = __int_as_float(p2.y), v3 = __int_as_float(p3.y);
            acc.x += v0 * g0.x; acc.y += v0 * g0.y; acc.z += v0 * g0.z; acc.w += v0 * g0.w;
            acc.x += v1 * g1.x; acc.y += v1 * g1.y; acc.z += v1 * g1.z; acc.w += v1 * g1.w;
            acc.x += v2 * g2.x; acc.y += v2 * g2.y; acc.z += v2 * g2.z; acc.w += v2 * g2.w;
            acc.x += v3 * g3.x; acc.y += v3 * g3.y; acc.z += v3 * g3.z; acc.w += v3 * g3.w;
        }
        for (; e < end; e++) {
            int2 p0 = pairs[e];
            float4 g0 = xv[(size_t)p0.x * Q + q];
            float v0 = __int_as_float(p0.y);
            acc.x += v0 * g0.x; acc.y += v0 * g0.y; acc.z += v0 * g0.z; acc.w += v0 * g0.w;
        }
        float4 xr = xv[(size_t)row * Q + q];
        float4 h1 = make_float4(xr.x + acc.x, xr.y + acc.y, xr.z + acc.z, xr.w + acc.w);
        float4 h2 = make_float4(xr.x * acc.x, xr.y * acc.y, xr.z * acc.z, xr.w * acc.w);
        *reinterpret_cast<float4*>(&hb[0][lr][q * 4]) = h1;
        *reinterpret_cast<float4*>(&hb[1][lr][q * 4]) = h2;
    }
    __syncthreads();
    if (row >= N) return;

    float a0 = b1[q], a1 = b1[q + Q], a2 = b2[q], a3 = b2[q + Q];
    const float4* w1v = reinterpret_cast<const float4*>(sW1);
    const float4* w2v = reinterpret_cast<const float4*>(sW2);
    const float4* h1v = reinterpret_cast<const float4*>(&hb[0][lr][0]);
    const float4* h2v = reinterpret_cast<const float4*>(&hb[1][lr][0]);
#pragma unroll
    for (int k4 = 0; k4 < DIN / 4; k4++) {
        float4 h1 = h1v[k4];
        float4 h2 = h2v[k4];
        float4 wa = w1v[q * LD4 + k4];
        float4 wb = w1v[(q + Q) * LD4 + k4];
        float4 wc = w2v[q * LD4 + k4];
        float4 wd = w2v[(q + Q) * LD4 + k4];
        a0 += h1.x * wa.x + h1.y * wa.y + h1.z * wa.z + h1.w * wa.w;
        a1 += h1.x * wb.x + h1.y * wb.y + h1.z * wb.z + h1.w * wb.w;
        a2 += h2.x * wc.x + h2.y * wc.y + h2.z * wc.z + h2.w * wc.w;
        a3 += h2.x * wd.x + h2.y * wd.y + h2.z * wd.z + h2.w * wd.w;
    }
    float y0 = leaky(a0) + leaky(a2);
    float y1 = leaky(a1) + leaky(a3);
    float nrm = y0 * y0 + y1 * y1;
#pragma unroll
    for (int m = 1; m < Q; m <<= 1) nrm += __shfl_xor(nrm, m, 64);
    float inv = 1.0f / fmaxf(sqrtf(nrm), 1e-12f);
    if (xnext) {
        xnext[(size_t)row * DOUT + q]     = y0;
        xnext[(size_t)row * DOUT + q + Q] = y1;
    }
    float* o = out + (size_t)row * 112 + out_col0;
    o[q]     = y0 * inv;
    o[q + Q] = y1 * inv;
}

extern "C" void kernel_launch(void* const* d_in, const int* in_sizes, int n_in,
                              void* d_out, int out_size, void* d_ws, size_t ws_size,
                              hipStream_t stream) {
    const float* Eemb = (const float*)d_in[0];
    const float* ev   = (const float*)d_in[1];
    const int*   rows = (const int*)d_in[2];
    const int*   cols = (const int*)d_in[3];
    const float* W1_0 = (const float*)d_in[4];
    const float* b1_0 = (const float*)d_in[5];
    const float* W2_0 = (const float*)d_in[6];
    const float* b2_0 = (const float*)d_in[7];
    const float* W1_1 = (const float*)d_in[8];
    const float* b1_1 = (const float*)d_in[9];
    const float* W2_1 = (const float*)d_in[10];
    const float* b2_1 = (const float*)d_in[11];
    float* out = (float*)d_out;

    int N  = in_sizes[0] / 64;
    int NE = in_sizes[1];
    int P  = (N + PROWS - 1) >> PSHIFT;   // 147

    size_t pairs_b  = (size_t)NE * sizeof(int2);
    size_t rowend_b = ((size_t)N * sizeof(int) + 255) & ~(size_t)255;
    size_t small_b  = 3 * 256 * sizeof(int);
    size_t x1_b     = ((size_t)N * 32 * sizeof(float) + 255) & ~(size_t)255;
    size_t ebf_b    = (size_t)N * 64 * sizeof(unsigned short);

    int2*  pairs   = (int2*)d_ws;
    int*   row_end = (int*)((char*)d_ws + pairs_b);
    int*   pcnt    = (int*)((char*)d_ws + pairs_b + rowend_b);
    int*   pbase   = pcnt + 256;
    int*   gcur    = pcnt + 512;
    float* x1      = (float*)((char*)d_ws + pairs_b + rowend_b + small_b);
    unsigned short* Ebf = (unsigned short*)((char*)d_ws + pairs_b + rowend_b + small_b + x1_b);

    bool use_bf = ws_size >= pairs_b + rowend_b + small_b + x1_b + ebf_b;

    int2* tmp = (int2*)d_out;  // 38.4MB scratch, dead until copy_E

    hipMemsetAsync(pcnt, 0, 256 * sizeof(int), stream);
    part_hist_kernel<<<256, 1024, P * sizeof(int), stream>>>(rows, pcnt, NE, P);
    part_scan_kernel<<<1, 256, 0, stream>>>(pcnt, pbase, gcur, P, NE);
    group_flush_kernel<<<(NE + GF_E - 1) / GF_E, GF_T, 0, stream>>>(
        rows, cols, ev, gcur, tmp, NE, P);
    row_sort_kernel<<<P, 1024, 0, stream>>>(tmp, pairs, pbase, row_end, N);

    copy_E_kernel<<<(N * 16 + 255) / 256, 256, 0, stream>>>(
        Eemb, out, use_bf ? Ebf : nullptr, N);

    if (use_bf) {
        pull_layer_bf16_kernel<64, 32><<<(N + 15) / 16, 256, 0, stream>>>(
            Eemb, Ebf, pairs, row_end, W1_0, b1_0, W2_0, b2_0, x1, out, 64, N);
    } else {
        pull_layer_kernel<64, 32><<<(N + 15) / 16, 256, 0, stream>>>(
            Eemb, pairs, row_end, W1_0, b1_0, W2_0, b2_0, x1, out, 64, N);
    }
    pull_layer_kernel<32, 16><<<(N + 31) / 32, 256, 0, stream>>>(
        x1, pairs, row_end, W1_1, b1_1, W2_1, b2_1, nullptr, out, 96, N);
}